// Round 10
// baseline (167.113 us; speedup 1.0000x reference)
//
#include <hip/hip_runtime.h>
#include <cstdint>
#include <cmath>

typedef unsigned short u16;
typedef __attribute__((ext_vector_type(8))) short bf16x8;
typedef __attribute__((ext_vector_type(4))) float f32x4;
typedef __attribute__((ext_vector_type(8))) unsigned short u16x8;
typedef __attribute__((ext_vector_type(4))) unsigned short u16x4;

#define DEV static __device__ __forceinline__

DEV u16 f2bf(float f) {
  union { float f; uint32_t u; } v; v.f = f;
  uint32_t r = (v.u + 0x7fffu + ((v.u >> 16) & 1u)) >> 16;
  return (u16)r;
}

DEV float fexp2(float x) { return exp2f(x); }  // v_exp_f32

DEV void async16(void* lds, const void* g) {
  __builtin_amdgcn_global_load_lds(
      (const __attribute__((address_space(1))) uint32_t*)g,
      (__attribute__((address_space(3))) uint32_t*)lds, 16, 0, 0);
}

// log2(e) / sqrt(1024): folded into Q at the GEMM1 epilogue
#define QSCALE 0.04508422002778011f

// ---------------- conversion kernels ----------------
__global__ void conv8(const float* __restrict__ in, u16* __restrict__ out, int n8) {
  int i = blockIdx.x * 256 + threadIdx.x;
  if (i >= n8) return;
  const float4* p = (const float4*)in + (size_t)i * 2;
  float4 a = p[0], b = p[1];
  u16x8 ov;
  ov[0] = f2bf(a.x); ov[1] = f2bf(a.y); ov[2] = f2bf(a.z); ov[3] = f2bf(a.w);
  ov[4] = f2bf(b.x); ov[5] = f2bf(b.y); ov[6] = f2bf(b.z); ov[7] = f2bf(b.w);
  *(u16x8*)(out + (size_t)i * 8) = ov;
}

// out[c][r] = bf16(in[r][c]);  R,C multiples of 32
__global__ void tconv(const float* __restrict__ in, u16* __restrict__ out, int R, int Cdim) {
  __shared__ float t[32][33];
  const int tx = threadIdx.x & 31, ty = threadIdx.x >> 5;
  const int r0 = blockIdx.y * 32, c0 = blockIdx.x * 32;
#pragma unroll
  for (int k = 0; k < 4; ++k) {
    int r = ty + k * 8;
    t[r][tx] = in[(size_t)(r0 + r) * Cdim + c0 + tx];
  }
  __syncthreads();
#pragma unroll
  for (int k = 0; k < 4; ++k) {
    int cc = ty + k * 8;
    out[(size_t)(c0 + cc) * R + r0 + tx] = f2bf(t[tx][cc]);
  }
}

// ---------------- GEMM (128x128, m97-structure): C = A*BT^T + bias ----------------
// Known-good R6 structure: single-buffered LDS, lockstep __syncthreads drain
// (keeps blocks synchronized on the same K-step -> L2-hit A/B panels).
template <int EPI>
__global__ __launch_bounds__(256, 2) void gemm_bt(
    const u16* __restrict__ A, const u16* __restrict__ BT,
    const float* __restrict__ bias, float* __restrict__ C,
    u16* __restrict__ qb, u16* __restrict__ kbuf, u16* __restrict__ vtb,
    int Mdim, int Ndim, int Kdim)
{
  __shared__ u16 Alds[128 * 64];
  __shared__ u16 Blds[128 * 64];
  const int tid = threadIdx.x;
  const int wid = tid >> 6, lane = tid & 63;
  const int g = lane >> 4, c = lane & 15;
  const int wr = wid >> 1, wc = wid & 1;
  // XCD-aware bijective swizzle (nwg % 8 == 0 for all our launches)
  const int gx = gridDim.x;
  const int nwg = gx * gridDim.y;
  const int lin = blockIdx.y * gx + blockIdx.x;
  const int work = (lin & 7) * (nwg >> 3) + (lin >> 3);
  const int row0 = (work / gx) * 128, col0 = (work % gx) * 128;

  f32x4 acc[4][4] = {};

  for (int kt = 0; kt < Kdim; kt += 64) {
    __syncthreads();
#pragma unroll
    for (int it = 0; it < 4; ++it) {
      int chunk = wid * 256 + it * 64 + lane;
      int r = chunk >> 3, j = chunk & 7;
      int js = j ^ (r & 7);   // pre-swizzled global source, linear LDS dest
      async16((char*)Alds + chunk * 16,
              A + (size_t)(row0 + r) * Kdim + kt + js * 8);
      async16((char*)Blds + chunk * 16,
              BT + (size_t)(col0 + r) * Kdim + kt + js * 8);
    }
    __syncthreads();
#pragma unroll
    for (int kk = 0; kk < 2; ++kk) {
      bf16x8 av[4], bv[4];
#pragma unroll
      for (int mi = 0; mi < 4; ++mi) {
        int r = wr * 64 + mi * 16 + c;
        int js = (kk * 4 + g) ^ (r & 7);
        av[mi] = *(const bf16x8*)((const char*)Alds + r * 128 + js * 16);
      }
#pragma unroll
      for (int ni = 0; ni < 4; ++ni) {
        int r = wc * 64 + ni * 16 + c;
        int js = (kk * 4 + g) ^ (r & 7);
        bv[ni] = *(const bf16x8*)((const char*)Blds + r * 128 + js * 16);
      }
#pragma unroll
      for (int mi = 0; mi < 4; ++mi)
#pragma unroll
        for (int ni = 0; ni < 4; ++ni)
          acc[mi][ni] = __builtin_amdgcn_mfma_f32_16x16x32_bf16(
              av[mi], bv[ni], acc[mi][ni], 0, 0, 0);
    }
  }

#pragma unroll
  for (int mi = 0; mi < 4; ++mi) {
#pragma unroll
    for (int ni = 0; ni < 4; ++ni) {
      int colg = col0 + wc * 64 + ni * 16 + c;
      float bsv = bias[colg];
      int rowb = row0 + wr * 64 + mi * 16 + g * 4;
      if (EPI == 0) {
#pragma unroll
        for (int r = 0; r < 4; ++r)
          C[(size_t)(rowb + r) * Ndim + colg] = acc[mi][ni][r] + bsv;
      } else {
        int t = colg >> 10, rem = colg & 1023;   // t uniform per (ni)
        int h = rem >> 6, hd = rem & 63;
        int b = rowb >> 11, s0 = rowb & 2047;    // 4 consecutive s per lane
        size_t bho = (size_t)(b * 16 + h);
        if (t == 2) {
          // packed 8B store: 4 consecutive s along the lane's r dim
          u16x4 pv;
#pragma unroll
          for (int r = 0; r < 4; ++r) pv[r] = f2bf(acc[mi][ni][r] + bsv);
          *(u16x4*)(vtb + (bho * 64 + hd) * 2048 + s0) = pv;
        } else {
          u16* dst = (t == 0) ? qb : kbuf;
          float sc = (t == 0) ? QSCALE : 1.0f;
#pragma unroll
          for (int r = 0; r < 4; ++r)
            dst[(bho * 2048 + (s0 + r)) * 64 + hd] = f2bf((acc[mi][ni][r] + bsv) * sc);
        }
      }
    }
  }
}

// ---------------- banded flash attention ----------------
// 512 blocks x 512 threads. Block: 128 q-rows, 8 waves x 16 rows.
// Swapped QK^T (mfma(K,Q)): lane (g,c) owns q-row qr0+c.
// Double-buffered K/V (48 KB LDS -> 3 blocks/CU), T3-minimal schedule:
// wait vmcnt(0) -> barrier -> STAGE(next) -> compute(cur).
// K/V per XCD = 4 bh x 512KB = 2MB < 4MB L2, so 1-deep prefetch suffices.
__global__ __launch_bounds__(512, 4) void attn_win(
    const u16* __restrict__ qb, const u16* __restrict__ kb,
    const u16* __restrict__ vtb, u16* __restrict__ hb)
{
  constexpr int S = 2048, W = 256;
  __shared__ u16 Klds[2][64 * 64];   // [key][hd], XOR-swizzled
  __shared__ u16 Vlds[2][64 * 64];   // [hd][key], XOR-swizzled
  __shared__ u16 Plds[8][16 * 64];   // per-wave [qrow][key], XOR-swizzled

  const int tid = threadIdx.x, wid = tid >> 6, lane = tid & 63;
  const int g = lane >> 4, c = lane & 15;
  // XCD swizzle: 512 blocks -> chunks of 64 consecutive work ids per XCD
  const int lin = blockIdx.x;
  const int work = (lin & 7) * 64 + (lin >> 3);
  const int qt = work & 15, bh = work >> 4;
  const int q0 = qt * 128;
  const int qr0 = q0 + wid * 16;     // this wave's 16 q-rows
  const int qw = qr0 + c;            // this thread's q-row
  const size_t bho = (size_t)bh * S * 64;

  bf16x8 aq[2];
  {
    const u16* qrow = qb + bho + (size_t)qw * 64;
    aq[0] = *(const bf16x8*)(qrow + g * 8);
    aq[1] = *(const bf16x8*)(qrow + 32 + g * 8);
  }
  f32x4 o[4] = {};
  float m = -1e30f, lsum = 0.f;

  const int kstart = (q0 - W > 0) ? (q0 - W) : 0;           // multiple of 64
  const int kend = (q0 + 128 + W < S) ? (q0 + 128 + W) : S; // multiple of 64
  const int ntiles = (kend - kstart) >> 6;                  // 6..10

  // one 16B chunk of K and of V per thread covers a full 64x64 tile
  const int sr = tid >> 3, sj = tid & 7;
  const int sjs = sj ^ (sr & 7);
#define STAGE(buf, k0s)                                                         \
  {                                                                             \
    async16((char*)&Klds[buf][0] + tid * 16,                                    \
            kb + bho + (size_t)((k0s) + sr) * 64 + sjs * 8);                    \
    async16((char*)&Vlds[buf][0] + tid * 16,                                    \
            vtb + bho + (size_t)sr * S + (k0s) + sjs * 8);                      \
  }

  STAGE(0, kstart);

  for (int i = 0; i < ntiles; ++i) {
    const int k0 = kstart + (i << 6);
    asm volatile("s_waitcnt vmcnt(0)" ::: "memory");  // tile i landed
    __builtin_amdgcn_s_barrier();                     // collective; prev buf free
    __builtin_amdgcn_sched_barrier(0);
    if (i + 1 < ntiles) STAGE((i + 1) & 1, k0 + 64);  // hides under compute(i)

    const int cur = i & 1;
    // wave-level skip: this wave's 16 rows entirely out of band for this tile
    const bool wave_active = !(k0 > qr0 + 15 + W) && !(k0 + 63 < qr0 - W);
    if (wave_active) {
      const u16* Kb = &Klds[cur][0];
      const u16* Vb = &Vlds[cur][0];

      // swapped QK^T: sacc[kb4][r] = S[q=qw][key=k0+kb4*16+g*4+r]
      f32x4 sacc[4] = {};
      __builtin_amdgcn_s_setprio(1);
#pragma unroll
      for (int kb4 = 0; kb4 < 4; ++kb4) {
        int krow = kb4 * 16 + c;
#pragma unroll
        for (int kk = 0; kk < 2; ++kk) {
          int js = (kk * 4 + g) ^ (krow & 7);
          bf16x8 bk = *(const bf16x8*)((const char*)Kb + krow * 128 + js * 16);
          sacc[kb4] = __builtin_amdgcn_mfma_f32_16x16x32_bf16(bk, aq[kk], sacc[kb4], 0, 0, 0);
        }
      }
      __builtin_amdgcn_s_setprio(0);

      const bool full = (k0 >= qr0 + 15 - W) && (k0 + 63 <= qr0 + W);
      float sl[4][4];
      if (full) {
#pragma unroll
        for (int kb4 = 0; kb4 < 4; ++kb4)
#pragma unroll
          for (int r = 0; r < 4; ++r) sl[kb4][r] = sacc[kb4][r];
      } else {
#pragma unroll
        for (int kb4 = 0; kb4 < 4; ++kb4) {
#pragma unroll
          for (int r = 0; r < 4; ++r) {
            int key = k0 + kb4 * 16 + g * 4 + r;
            int d = qw - key;
            bool valid = (d <= W) && (d >= -W);
            sl[kb4][r] = valid ? sacc[kb4][r] : -1e30f;
          }
        }
      }

      // row max: 15 in-thread + 2 cross-group shfl
      float mx = fmaxf(
          fmaxf(fmaxf(fmaxf(sl[0][0], sl[0][1]), fmaxf(sl[0][2], sl[0][3])),
                fmaxf(fmaxf(sl[1][0], sl[1][1]), fmaxf(sl[1][2], sl[1][3]))),
          fmaxf(fmaxf(fmaxf(sl[2][0], sl[2][1]), fmaxf(sl[2][2], sl[2][3])),
                fmaxf(fmaxf(sl[3][0], sl[3][1]), fmaxf(sl[3][2], sl[3][3]))));
      mx = fmaxf(mx, __shfl_xor(mx, 16));
      mx = fmaxf(mx, __shfl_xor(mx, 32));

      // defer-max (T13): rescale only when max grew by more than THR=8
      if (!__all(mx - m <= 8.0f)) {
        float mnew = fmaxf(m, mx);
        float fs = fexp2(m - mnew);
        m = mnew;
        lsum *= fs;
        float fsr[4];
#pragma unroll
        for (int r = 0; r < 4; ++r)
          fsr[r] = __shfl(fs, (lane & 48) | (((lane & 48) >> 2) + r));
#pragma unroll
        for (int nb = 0; nb < 4; ++nb)
#pragma unroll
          for (int r = 0; r < 4; ++r) o[nb][r] *= fsr[r];
      }

      // exp + pack to bf16 (cvt_pk) + 4x ds_write_b64
      float rsum = 0.f;
      u16* Pw = &Plds[wid][0];
#pragma unroll
      for (int kb4 = 0; kb4 < 4; ++kb4) {
        float p0, p1, p2, p3;
        if (full) {
          p0 = fexp2(sl[kb4][0] - m); p1 = fexp2(sl[kb4][1] - m);
          p2 = fexp2(sl[kb4][2] - m); p3 = fexp2(sl[kb4][3] - m);
        } else {
          p0 = (sl[kb4][0] > -1e29f) ? fexp2(sl[kb4][0] - m) : 0.f;
          p1 = (sl[kb4][1] > -1e29f) ? fexp2(sl[kb4][1] - m) : 0.f;
          p2 = (sl[kb4][2] > -1e29f) ? fexp2(sl[kb4][2] - m) : 0.f;
          p3 = (sl[kb4][3] > -1e29f) ? fexp2(sl[kb4][3] - m) : 0.f;
        }
        rsum += (p0 + p1) + (p2 + p3);
        uint32_t lo, hi;
        asm("v_cvt_pk_bf16_f32 %0, %1, %2" : "=v"(lo) : "v"(p0), "v"(p1));
        asm("v_cvt_pk_bf16_f32 %0, %1, %2" : "=v"(hi) : "v"(p2), "v"(p3));
        uint2 wv; wv.x = lo; wv.y = hi;
        *(uint2*)((char*)Pw + c * 128 + (((kb4 * 2 + (g >> 1)) ^ (c & 7)) << 4) +
                  ((g & 1) << 3)) = wv;
      }
      rsum += __shfl_xor(rsum, 16);
      rsum += __shfl_xor(rsum, 32);
      lsum += rsum;

      asm volatile("s_waitcnt lgkmcnt(0)" ::: "memory");  // P visible within wave
      __builtin_amdgcn_sched_barrier(0);
      __builtin_amdgcn_s_setprio(1);
#pragma unroll
      for (int ks = 0; ks < 2; ++ks) {
        int js = (ks * 4 + g) ^ (c & 7);
        bf16x8 pa = *(const bf16x8*)((const char*)Pw + c * 128 + js * 16);
#pragma unroll
        for (int nb = 0; nb < 4; ++nb) {
          int hd = nb * 16 + c;
          int vjs = (ks * 4 + g) ^ (hd & 7);
          bf16x8 bv = *(const bf16x8*)((const char*)Vb + hd * 128 + vjs * 16);
          o[nb] = __builtin_amdgcn_mfma_f32_16x16x32_bf16(pa, bv, o[nb], 0, 0, 0);
        }
      }
      __builtin_amdgcn_s_setprio(0);
    }
  }
#undef STAGE

  const int b = bh >> 4, h = bh & 15;
  float linv[4];
#pragma unroll
  for (int r = 0; r < 4; ++r)
    linv[r] = 1.0f / __shfl(lsum, (lane & 48) | (((lane & 48) >> 2) + r));
#pragma unroll
  for (int r = 0; r < 4; ++r) {
    int qr = qr0 + g * 4 + r;
#pragma unroll
    for (int nb = 0; nb < 4; ++nb) {
      int col = h * 64 + nb * 16 + c;
      hb[(size_t)(b * 2048 + qr) * 1024 + col] = f2bf(o[nb][r] * linv[r]);
    }
  }
}

// ---------------- launch ----------------
extern "C" void kernel_launch(void* const* d_in, const int* in_sizes, int n_in,
                              void* d_out, int out_size, void* d_ws, size_t ws_size,
                              hipStream_t stream) {
  const float* x     = (const float*)d_in[0];
  const float* w_qkv = (const float*)d_in[1];
  const float* b_qkv = (const float*)d_in[2];
  const float* w_out = (const float*)d_in[3];
  const float* b_out = (const float*)d_in[4];
  float* out = (float*)d_out;

  char* ws = (char*)d_ws;
  const size_t MB = 1024 * 1024;
  u16* xbf   = (u16*)(ws);            // 8 MB  x bf16 [4096][1024]
  u16* wqT   = (u16*)(ws + 8 * MB);   // 6 MB  w_qkv^T bf16 [3072][1024]
  u16* woT   = (u16*)(ws + 14 * MB);  // 2 MB  w_out^T bf16 [1024][1024]
  u16* qbuf  = (u16*)(ws + 16 * MB);  // 8 MB  [B,H,S,64] (pre-scaled by QSCALE)
  u16* kbuf  = (u16*)(ws + 24 * MB);  // 8 MB  [B,H,S,64]
  u16* vtbuf = (u16*)(ws + 32 * MB);  // 8 MB  [B,H,64,S]
  u16* hbuf  = (u16*)(ws + 40 * MB);  // 8 MB  attn out [4096][1024]

  conv8<<<dim3(4096 * 1024 / 8 / 256), 256, 0, stream>>>(x, xbf, 4096 * 1024 / 8);
  tconv<<<dim3(3072 / 32, 1024 / 32), 256, 0, stream>>>(w_qkv, wqT, 1024, 3072);
  tconv<<<dim3(1024 / 32, 1024 / 32), 256, 0, stream>>>(w_out, woT, 1024, 1024);
  gemm_bt<1><<<dim3(3072 / 128, 4096 / 128), 256, 0, stream>>>(
      xbf, wqT, b_qkv, nullptr, qbuf, kbuf, vtbuf, 4096, 3072, 1024);
  attn_win<<<dim3(512), 512, 0, stream>>>(qbuf, kbuf, vtbuf, hbuf);
  gemm_bt<0><<<dim3(1024 / 128, 4096 / 128), 256, 0, stream>>>(
      hbuf, woT, b_out, out, nullptr, nullptr, nullptr, 4096, 1024, 1024);
}

// Round 12
// 160.479 us; speedup vs baseline: 1.0413x; 1.0413x over previous
//
#include <hip/hip_runtime.h>
#include <cstdint>
#include <cmath>

typedef unsigned short u16;
typedef __attribute__((ext_vector_type(8))) short bf16x8;
typedef __attribute__((ext_vector_type(4))) float f32x4;
typedef __attribute__((ext_vector_type(8))) unsigned short u16x8;
typedef __attribute__((ext_vector_type(4))) unsigned short u16x4;

#define DEV static __device__ __forceinline__

DEV u16 f2bf(float f) {
  union { float f; uint32_t u; } v; v.f = f;
  uint32_t r = (v.u + 0x7fffu + ((v.u >> 16) & 1u)) >> 16;
  return (u16)r;
}

DEV float fexp2(float x) { return exp2f(x); }  // v_exp_f32

DEV void async16(void* lds, const void* g) {
  __builtin_amdgcn_global_load_lds(
      (const __attribute__((address_space(1))) uint32_t*)g,
      (__attribute__((address_space(3))) uint32_t*)lds, 16, 0, 0);
}

// log2(e) / sqrt(1024): folded into Q at the GEMM1 epilogue
#define QSCALE 0.04508422002778011f

// ---------------- conversion kernels ----------------
__global__ void conv8(const float* __restrict__ in, u16* __restrict__ out, int n8) {
  int i = blockIdx.x * 256 + threadIdx.x;
  if (i >= n8) return;
  const float4* p = (const float4*)in + (size_t)i * 2;
  float4 a = p[0], b = p[1];
  u16x8 ov;
  ov[0] = f2bf(a.x); ov[1] = f2bf(a.y); ov[2] = f2bf(a.z); ov[3] = f2bf(a.w);
  ov[4] = f2bf(b.x); ov[5] = f2bf(b.y); ov[6] = f2bf(b.z); ov[7] = f2bf(b.w);
  *(u16x8*)(out + (size_t)i * 8) = ov;
}

// out[c][r] = bf16(in[r][c]);  R,C multiples of 32
__global__ void tconv(const float* __restrict__ in, u16* __restrict__ out, int R, int Cdim) {
  __shared__ float t[32][33];
  const int tx = threadIdx.x & 31, ty = threadIdx.x >> 5;
  const int r0 = blockIdx.y * 32, c0 = blockIdx.x * 32;
#pragma unroll
  for (int k = 0; k < 4; ++k) {
    int r = ty + k * 8;
    t[r][tx] = in[(size_t)(r0 + r) * Cdim + c0 + tx];
  }
  __syncthreads();
#pragma unroll
  for (int k = 0; k < 4; ++k) {
    int cc = ty + k * 8;
    out[(size_t)(c0 + cc) * R + r0 + tx] = f2bf(t[tx][cc]);
  }
}

// ---------------- GEMM1 (128x128, m97-structure): qkv epilogue ----------------
// Known-good R6 structure: single-buffered LDS, lockstep __syncthreads drain
// (keeps blocks synchronized on the same K-step -> L2-hit A/B panels).
__global__ __launch_bounds__(256, 2) void gemm_qkv(
    const u16* __restrict__ A, const u16* __restrict__ BT,
    const float* __restrict__ bias,
    u16* __restrict__ qb, u16* __restrict__ kbuf, u16* __restrict__ vtb,
    int Kdim)
{
  __shared__ u16 Alds[128 * 64];
  __shared__ u16 Blds[128 * 64];
  const int tid = threadIdx.x;
  const int wid = tid >> 6, lane = tid & 63;
  const int g = lane >> 4, c = lane & 15;
  const int wr = wid >> 1, wc = wid & 1;
  const int gx = gridDim.x;
  const int nwg = gx * gridDim.y;
  const int lin = blockIdx.y * gx + blockIdx.x;
  const int work = (lin & 7) * (nwg >> 3) + (lin >> 3);
  const int row0 = (work / gx) * 128, col0 = (work % gx) * 128;

  f32x4 acc[4][4] = {};

  for (int kt = 0; kt < Kdim; kt += 64) {
    __syncthreads();
#pragma unroll
    for (int it = 0; it < 4; ++it) {
      int chunk = wid * 256 + it * 64 + lane;
      int r = chunk >> 3, j = chunk & 7;
      int js = j ^ (r & 7);   // pre-swizzled global source, linear LDS dest
      async16((char*)Alds + chunk * 16,
              A + (size_t)(row0 + r) * Kdim + kt + js * 8);
      async16((char*)Blds + chunk * 16,
              BT + (size_t)(col0 + r) * Kdim + kt + js * 8);
    }
    __syncthreads();
#pragma unroll
    for (int kk = 0; kk < 2; ++kk) {
      bf16x8 av[4], bv[4];
#pragma unroll
      for (int mi = 0; mi < 4; ++mi) {
        int r = wr * 64 + mi * 16 + c;
        int js = (kk * 4 + g) ^ (r & 7);
        av[mi] = *(const bf16x8*)((const char*)Alds + r * 128 + js * 16);
      }
#pragma unroll
      for (int ni = 0; ni < 4; ++ni) {
        int r = wc * 64 + ni * 16 + c;
        int js = (kk * 4 + g) ^ (r & 7);
        bv[ni] = *(const bf16x8*)((const char*)Blds + r * 128 + js * 16);
      }
#pragma unroll
      for (int mi = 0; mi < 4; ++mi)
#pragma unroll
        for (int ni = 0; ni < 4; ++ni)
          acc[mi][ni] = __builtin_amdgcn_mfma_f32_16x16x32_bf16(
              av[mi], bv[ni], acc[mi][ni], 0, 0, 0);
    }
  }

#pragma unroll
  for (int mi = 0; mi < 4; ++mi) {
#pragma unroll
    for (int ni = 0; ni < 4; ++ni) {
      int colg = col0 + wc * 64 + ni * 16 + c;
      float bsv = bias[colg];
      int rowb = row0 + wr * 64 + mi * 16 + g * 4;
      int t = colg >> 10, rem = colg & 1023;
      int h = rem >> 6, hd = rem & 63;
      int b = rowb >> 11, s0 = rowb & 2047;    // 4 consecutive s per lane
      size_t bho = (size_t)(b * 16 + h);
      if (t == 2) {
        u16x4 pv;   // packed 8B store: 4 consecutive s along the lane's r dim
#pragma unroll
        for (int r = 0; r < 4; ++r) pv[r] = f2bf(acc[mi][ni][r] + bsv);
        *(u16x4*)(vtb + (bho * 64 + hd) * 2048 + s0) = pv;
      } else {
        u16* dst = (t == 0) ? qb : kbuf;
        float sc = (t == 0) ? QSCALE : 1.0f;
#pragma unroll
        for (int r = 0; r < 4; ++r)
          dst[(bho * 2048 + (s0 + r)) * 64 + hd] = f2bf((acc[mi][ni][r] + bsv) * sc);
      }
    }
  }
}

// ---------------- GEMM2 (64x128 tile): C = A*BT^T + bias, f32 out -----------
// Grid 512 blocks = 2 blocks/CU (vs 256 = 1/CU at 128^2): drains get
// co-resident cover. 4 waves, 1M x 4N, LDS 24 KB.
__global__ __launch_bounds__(256, 4) void gemm_out(
    const u16* __restrict__ A, const u16* __restrict__ BT,
    const float* __restrict__ bias, float* __restrict__ C,
    int Ndim, int Kdim)
{
  __shared__ u16 Alds[64 * 64];    // [mrow][k], XOR-swizzled
  __shared__ u16 Blds[128 * 64];   // [ncol][k], XOR-swizzled
  const int tid = threadIdx.x;
  const int wid = tid >> 6, lane = tid & 63;
  const int g = lane >> 4, c = lane & 15;
  const int gx = gridDim.x;
  const int nwg = gx * gridDim.y;
  const int lin = blockIdx.y * gx + blockIdx.x;
  const int work = (lin & 7) * (nwg >> 3) + (lin >> 3);
  const int row0 = (work / gx) * 64, col0 = (work % gx) * 128;

  f32x4 acc[4][2] = {};

  for (int kt = 0; kt < Kdim; kt += 64) {
    __syncthreads();
#pragma unroll
    for (int it = 0; it < 2; ++it) {
      int chunk = it * 256 + tid;
      int r = chunk >> 3, j = chunk & 7;
      int js = j ^ (r & 7);
      async16((char*)Alds + chunk * 16,
              A + (size_t)(row0 + r) * Kdim + kt + js * 8);
    }
#pragma unroll
    for (int it = 0; it < 4; ++it) {
      int cb = it * 256 + tid;
      int r = cb >> 3, j = cb & 7;
      int js = j ^ (r & 7);
      async16((char*)Blds + cb * 16,
              BT + (size_t)(col0 + r) * Kdim + kt + js * 8);
    }
    __syncthreads();
#pragma unroll
    for (int kk = 0; kk < 2; ++kk) {
      bf16x8 av[4], bv[2];
#pragma unroll
      for (int mi = 0; mi < 4; ++mi) {
        int r = mi * 16 + c;
        int js = (kk * 4 + g) ^ (r & 7);
        av[mi] = *(const bf16x8*)((const char*)Alds + r * 128 + js * 16);
      }
#pragma unroll
      for (int ni = 0; ni < 2; ++ni) {
        int r = wid * 32 + ni * 16 + c;
        int js = (kk * 4 + g) ^ (r & 7);
        bv[ni] = *(const bf16x8*)((const char*)Blds + r * 128 + js * 16);
      }
#pragma unroll
      for (int mi = 0; mi < 4; ++mi)
#pragma unroll
        for (int ni = 0; ni < 2; ++ni)
          acc[mi][ni] = __builtin_amdgcn_mfma_f32_16x16x32_bf16(
              av[mi], bv[ni], acc[mi][ni], 0, 0, 0);
    }
  }

#pragma unroll
  for (int mi = 0; mi < 4; ++mi) {
#pragma unroll
    for (int ni = 0; ni < 2; ++ni) {
      int colg = col0 + wid * 32 + ni * 16 + c;
      float bsv = bias[colg];
      int rowb = row0 + mi * 16 + g * 4;
#pragma unroll
      for (int r = 0; r < 4; ++r)
        C[(size_t)(rowb + r) * Ndim + colg] = acc[mi][ni][r] + bsv;
    }
  }
}

// ---------------- banded flash attention (R6 known-good) ----------------
// 512 blocks x 512 threads. Block: 128 q-rows, 8 waves x 16 rows.
// Swapped QK^T (mfma(K,Q)): lane (g,c) owns q-row qr0+c.
// Triple-buffered K/V, 2-deep prefetch, counted vmcnt, raw s_barrier.
__global__ __launch_bounds__(512, 4) void attn_win(
    const u16* __restrict__ qb, const u16* __restrict__ kb,
    const u16* __restrict__ vtb, u16* __restrict__ hb)
{
  constexpr int S = 2048, W = 256;
  __shared__ u16 Klds[3][64 * 64];   // [key][hd], XOR-swizzled
  __shared__ u16 Vlds[3][64 * 64];   // [hd][key], XOR-swizzled
  __shared__ u16 Plds[8][16 * 64];   // per-wave [qrow][key], XOR-swizzled

  const int tid = threadIdx.x, wid = tid >> 6, lane = tid & 63;
  const int g = lane >> 4, c = lane & 15;
  const int lin = blockIdx.x;
  const int work = (lin & 7) * 64 + (lin >> 3);
  const int qt = work & 15, bh = work >> 4;
  const int q0 = qt * 128;
  const int qr0 = q0 + wid * 16;     // this wave's 16 q-rows
  const int qw = qr0 + c;            // this thread's q-row
  const size_t bho = (size_t)bh * S * 64;

  bf16x8 aq[2];
  {
    const u16* qrow = qb + bho + (size_t)qw * 64;
    aq[0] = *(const bf16x8*)(qrow + g * 8);
    aq[1] = *(const bf16x8*)(qrow + 32 + g * 8);
  }
  f32x4 o[4] = {};
  float m = -1e30f, lsum = 0.f;

  const int kstart = (q0 - W > 0) ? (q0 - W) : 0;           // multiple of 64
  const int kend = (q0 + 128 + W < S) ? (q0 + 128 + W) : S; // multiple of 64
  const int ntiles = (kend - kstart) >> 6;                  // 6..10

  const int sr = tid >> 3, sj = tid & 7;
  const int sjs = sj ^ (sr & 7);
#define STAGE(buf, k0s)                                                         \
  {                                                                             \
    async16((char*)&Klds[buf][0] + tid * 16,                                    \
            kb + bho + (size_t)((k0s) + sr) * 64 + sjs * 8);                    \
    async16((char*)&Vlds[buf][0] + tid * 16,                                    \
            vtb + bho + (size_t)sr * S + (k0s) + sjs * 8);                      \
  }

  STAGE(0, kstart);
  if (ntiles > 1) STAGE(1, kstart + 64);

  for (int i = 0; i < ntiles; ++i) {
    const int k0 = kstart + (i << 6);
    if (i + 1 < ntiles) { asm volatile("s_waitcnt vmcnt(2)" ::: "memory"); }
    else                { asm volatile("s_waitcnt vmcnt(0)" ::: "memory"); }
    __builtin_amdgcn_s_barrier();        // collective: buf_i complete, buf_{i-1} free
    __builtin_amdgcn_sched_barrier(0);
    if (i + 2 < ntiles) STAGE((i + 2) % 3, k0 + 128);

    const int cur = i % 3;
    const bool wave_active = !(k0 > qr0 + 15 + W) && !(k0 + 63 < qr0 - W);
    if (wave_active) {
      const u16* Kb = &Klds[cur][0];
      const u16* Vb = &Vlds[cur][0];

      f32x4 sacc[4] = {};
      __builtin_amdgcn_s_setprio(1);
#pragma unroll
      for (int kb4 = 0; kb4 < 4; ++kb4) {
        int krow = kb4 * 16 + c;
#pragma unroll
        for (int kk = 0; kk < 2; ++kk) {
          int js = (kk * 4 + g) ^ (krow & 7);
          bf16x8 bk = *(const bf16x8*)((const char*)Kb + krow * 128 + js * 16);
          sacc[kb4] = __builtin_amdgcn_mfma_f32_16x16x32_bf16(bk, aq[kk], sacc[kb4], 0, 0, 0);
        }
      }
      __builtin_amdgcn_s_setprio(0);

      const bool full = (k0 >= qr0 + 15 - W) && (k0 + 63 <= qr0 + W);
      float sl[4][4];
      if (full) {
#pragma unroll
        for (int kb4 = 0; kb4 < 4; ++kb4)
#pragma unroll
          for (int r = 0; r < 4; ++r) sl[kb4][r] = sacc[kb4][r];
      } else {
#pragma unroll
        for (int kb4 = 0; kb4 < 4; ++kb4) {
#pragma unroll
          for (int r = 0; r < 4; ++r) {
            int key = k0 + kb4 * 16 + g * 4 + r;
            int d = qw - key;
            bool valid = (d <= W) && (d >= -W);
            sl[kb4][r] = valid ? sacc[kb4][r] : -1e30f;
          }
        }
      }

      float mx = fmaxf(
          fmaxf(fmaxf(fmaxf(sl[0][0], sl[0][1]), fmaxf(sl[0][2], sl[0][3])),
                fmaxf(fmaxf(sl[1][0], sl[1][1]), fmaxf(sl[1][2], sl[1][3]))),
          fmaxf(fmaxf(fmaxf(sl[2][0], sl[2][1]), fmaxf(sl[2][2], sl[2][3])),
                fmaxf(fmaxf(sl[3][0], sl[3][1]), fmaxf(sl[3][2], sl[3][3]))));
      mx = fmaxf(mx, __shfl_xor(mx, 16));
      mx = fmaxf(mx, __shfl_xor(mx, 32));

      if (!__all(mx - m <= 8.0f)) {
        float mnew = fmaxf(m, mx);
        float fs = fexp2(m - mnew);
        m = mnew;
        lsum *= fs;
        float fsr[4];
#pragma unroll
        for (int r = 0; r < 4; ++r)
          fsr[r] = __shfl(fs, (lane & 48) | (((lane & 48) >> 2) + r));
#pragma unroll
        for (int nb = 0; nb < 4; ++nb)
#pragma unroll
          for (int r = 0; r < 4; ++r) o[nb][r] *= fsr[r];
      }

      float rsum = 0.f;
      u16* Pw = &Plds[wid][0];
#pragma unroll
      for (int kb4 = 0; kb4 < 4; ++kb4) {
        float p0, p1, p2, p3;
        if (full) {
          p0 = fexp2(sl[kb4][0] - m); p1 = fexp2(sl[kb4][1] - m);
          p2 = fexp2(sl[kb4][2] - m); p3 = fexp2(sl[kb4][3] - m);
        } else {
          p0 = (sl[kb4][0] > -1e29f) ? fexp2(sl[kb4][0] - m) : 0.f;
          p1 = (sl[kb4][1] > -1e29f) ? fexp2(sl[kb4][1] - m) : 0.f;
          p2 = (sl[kb4][2] > -1e29f) ? fexp2(sl[kb4][2] - m) : 0.f;
          p3 = (sl[kb4][3] > -1e29f) ? fexp2(sl[kb4][3] - m) : 0.f;
        }
        rsum += (p0 + p1) + (p2 + p3);
        uint32_t lo, hi;
        asm("v_cvt_pk_bf16_f32 %0, %1, %2" : "=v"(lo) : "v"(p0), "v"(p1));
        asm("v_cvt_pk_bf16_f32 %0, %1, %2" : "=v"(hi) : "v"(p2), "v"(p3));
        uint2 wv; wv.x = lo; wv.y = hi;
        *(uint2*)((char*)Pw + c * 128 + (((kb4 * 2 + (g >> 1)) ^ (c & 7)) << 4) +
                  ((g & 1) << 3)) = wv;
      }
      rsum += __shfl_xor(rsum, 16);
      rsum += __shfl_xor(rsum, 32);
      lsum += rsum;

      asm volatile("s_waitcnt lgkmcnt(0)" ::: "memory");  // P visible within wave
      __builtin_amdgcn_sched_barrier(0);
      __builtin_amdgcn_s_setprio(1);
#pragma unroll
      for (int ks = 0; ks < 2; ++ks) {
        int js = (ks * 4 + g) ^ (c & 7);
        bf16x8 pa = *(const bf16x8*)((const char*)Pw + c * 128 + js * 16);
#pragma unroll
        for (int nb = 0; nb < 4; ++nb) {
          int hd = nb * 16 + c;
          int vjs = (ks * 4 + g) ^ (hd & 7);
          bf16x8 bv = *(const bf16x8*)((const char*)Vb + hd * 128 + vjs * 16);
          o[nb] = __builtin_amdgcn_mfma_f32_16x16x32_bf16(pa, bv, o[nb], 0, 0, 0);
        }
      }
      __builtin_amdgcn_s_setprio(0);
    }
  }
#undef STAGE

  const int b = bh >> 4, h = bh & 15;
  float linv[4];
#pragma unroll
  for (int r = 0; r < 4; ++r)
    linv[r] = 1.0f / __shfl(lsum, (lane & 48) | (((lane & 48) >> 2) + r));
#pragma unroll
  for (int r = 0; r < 4; ++r) {
    int qr = qr0 + g * 4 + r;
#pragma unroll
    for (int nb = 0; nb < 4; ++nb) {
      int col = h * 64 + nb * 16 + c;
      hb[(size_t)(b * 2048 + qr) * 1024 + col] = f2bf(o[nb][r] * linv[r]);
    }
  }
}

// ---------------- launch ----------------
extern "C" void kernel_launch(void* const* d_in, const int* in_sizes, int n_in,
                              void* d_out, int out_size, void* d_ws, size_t ws_size,
                              hipStream_t stream) {
  const float* x     = (const float*)d_in[0];
  const float* w_qkv = (const float*)d_in[1];
  const float* b_qkv = (const float*)d_in[2];
  const float* w_out = (const float*)d_in[3];
  const float* b_out = (const float*)d_in[4];
  float* out = (float*)d_out;

  char* ws = (char*)d_ws;
  const size_t MB = 1024 * 1024;
  u16* xbf   = (u16*)(ws);            // 8 MB  x bf16 [4096][1024]
  u16* wqT   = (u16*)(ws + 8 * MB);   // 6 MB  w_qkv^T bf16 [3072][1024]
  u16* woT   = (u16*)(ws + 14 * MB);  // 2 MB  w_out^T bf16 [1024][1024]
  u16* qbuf  = (u16*)(ws + 16 * MB);  // 8 MB  [B,H,S,64] (pre-scaled by QSCALE)
  u16* kbuf  = (u16*)(ws + 24 * MB);  // 8 MB  [B,H,S,64]
  u16* vtbuf = (u16*)(ws + 32 * MB);  // 8 MB  [B,H,64,S]
  u16* hbuf  = (u16*)(ws + 40 * MB);  // 8 MB  attn out [4096][1024]

  conv8<<<dim3(4096 * 1024 / 8 / 256), 256, 0, stream>>>(x, xbf, 4096 * 1024 / 8);
  tconv<<<dim3(3072 / 32, 1024 / 32), 256, 0, stream>>>(w_qkv, wqT, 1024, 3072);
  tconv<<<dim3(1024 / 32, 1024 / 32), 256, 0, stream>>>(w_out, woT, 1024, 1024);
  gemm_qkv<<<dim3(3072 / 128, 4096 / 128), 256, 0, stream>>>(
      xbf, wqT, b_qkv, qbuf, kbuf, vtbuf, 1024);
  attn_win<<<dim3(512), 512, 0, stream>>>(qbuf, kbuf, vtbuf, hbuf);
  gemm_out<<<dim3(1024 / 128, 4096 / 64), 256, 0, stream>>>(
      hbuf, woT, b_out, out, 1024, 1024);
}